// Round 20
// baseline (157.038 us; speedup 1.0000x reference)
//
#include <hip/hip_runtime.h>
#include <hip/hip_bf16.h>
#include <stdint.h>

#define B_   8
#define N_   4096
#define K1_  17
#define D_   256
#define NT_  (B_*N_)          // 32768
#define E16_ (NT_*16)         // 524288
#define NP_  (NT_*D_)         // 8388608
#define EPS_ 1e-5f

typedef __attribute__((ext_vector_type(8))) short short8v;  // 8 bf16 (4 VGPR)
typedef __attribute__((ext_vector_type(4))) float f32x4;

// f32 -> bf16 RNE, pure C
__device__ __forceinline__ unsigned short f2bfu(float f){
  unsigned u = __float_as_uint(f);
  unsigned r = (u + 0x7FFFu + ((u>>16)&1u)) >> 16;
  return (unsigned short)r;
}
__device__ __forceinline__ short f2bf(float f){ return (short)f2bfu(f); }
__device__ __forceinline__ unsigned pkbf(float lo, float hi){
  return (unsigned)f2bfu(lo) | ((unsigned)f2bfu(hi) << 16);
}
__device__ __forceinline__ float bf2f(short s){
  return __uint_as_float(((unsigned)(unsigned short)s) << 16);
}
__device__ __forceinline__ void unpack2(unsigned u, float& lo, float& hi){
  lo = __uint_as_float(u << 16);
  hi = __uint_as_float(u & 0xFFFF0000u);
}

// ---------------- prep: weight transpose + degcnt zero + mask detect --------
__global__ __launch_bounds__(256) void k_prep(const float* __restrict__ W0,
                                              const float* __restrict__ W1,
                                              short* __restrict__ Wt0,
                                              short* __restrict__ Wt1,
                                              int* __restrict__ degcnt,
                                              const unsigned int* __restrict__ mw,
                                              int* __restrict__ flag){
  if (blockIdx.x < 128){
    const float* W  = (blockIdx.x & 1) ? W1  : W0;
    short*       Wt = (blockIdx.x & 1) ? Wt1 : Wt0;
    int tile = blockIdx.x >> 1;
    int ti = tile >> 3, tj = tile & 7;
    __shared__ float sm[32][33];
    int r = threadIdx.x >> 5, c = threadIdx.x & 31;
    #pragma unroll
    for (int i=0;i<4;i++)
      sm[r + i*8][c] = W[(ti*32 + r + i*8)*256 + tj*32 + c];
    __syncthreads();
    #pragma unroll
    for (int i=0;i<4;i++){
      int rr = r + i*8;
      Wt[(size_t)(tj*32 + rr)*256 + ti*32 + c] = f2bf(sm[c][rr]);
    }
  } else {
    int ib = blockIdx.x - 128;
    int i  = ib*256 + threadIdx.x;
    degcnt[i] = 0;
    if (ib == 0){
      __shared__ int s_int, s_f32;
      if (threadIdx.x==0){ s_int=1; s_f32=1; }
      __syncthreads();
      int bad_i=0, bad_f=0;
      #pragma unroll
      for (int j=0;j<4;j++){
        unsigned w = mw[threadIdx.x*4 + j];
        if (!(w==0u || w==1u))          bad_i=1;
        if (!(w==0u || w==0x3F800000u)) bad_f=1;
      }
      if (bad_i) atomicAnd(&s_int, 0);
      if (bad_f) atomicAnd(&s_f32, 0);
      __syncthreads();
      if (threadIdx.x==0) *flag = s_int ? 0 : (s_f32 ? 1 : 2);
    }
  }
}

__device__ __forceinline__ bool mask_at(const void* maskp, int f, int idx){
  if (f==0) return ((const int*)maskp)[idx] != 0;
  if (f==1) return ((const float*)maskp)[idx] != 0.0f;
  return ((const unsigned char*)maskp)[idx] != 0;
}

// deg: XCD-batch-swizzled edge ranges (batch b -> XCD b; local-L2 atomics)
__global__ void k_deg(const int* __restrict__ knn, const void* __restrict__ maskp,
                      const int* __restrict__ flag, int* __restrict__ degcnt){
  int f = *flag;
  int bid = blockIdx.x;                                  // 2048 blocks x 256
  int e = ((bid & 7) << 16) + ((bid >> 3) << 8) + threadIdx.x;
  int node = e >> 4;
  int k    = (e & 15) + 1;
  int idx  = node*K1_ + k;
  if (mask_at(maskp, f, idx)){
    int b   = node >> 12;
    int dst = knn[idx] + (b<<12);
    atomicAdd(&degcnt[dst], 1);
  }
}

// wave-shfl scan: 1024 thr = 16 waves; 6 shfl steps + ONE barrier
__global__ void k_scan(const int* __restrict__ degcnt, int* __restrict__ rowptr,
                       int* __restrict__ fillptr, float* __restrict__ dinv){
  __shared__ int wsum[16];
  int t = threadIdx.x;
  int lane = t & 63, wid = t >> 6;
  int base = t*32;
  int loc[32]; int tot = 0;
  #pragma unroll
  for (int i=0;i<32;i++){ loc[i] = degcnt[base+i]; tot += loc[i]; }
  int inc = tot;
  #pragma unroll
  for (int off=1; off<64; off<<=1){
    int v = __shfl_up(inc, off, 64);
    if (lane >= off) inc += v;
  }
  if (lane == 63) wsum[wid] = inc;
  __syncthreads();
  int woff = 0;
  #pragma unroll
  for (int i=0;i<16;i++) if (i < wid) woff += wsum[i];
  int run = woff + inc - tot;          // exclusive prefix
  #pragma unroll
  for (int i=0;i<32;i++){
    int v = base+i;
    rowptr[v]  = run;
    fillptr[v] = run;
    dinv[v]    = rsqrtf((float)loc[i] + 1.0f);
    run += loc[i];
  }
  if (t==1023) rowptr[NT_] = run;
}

// ---------------- double-buffered MFMA GEMM (tile 128x256, BK=32) -----------
// 8 K-steps, one barrier each; ds_write targets the other buffer; DEPTH-3
// register pipeline (2 reg sets): load for k(kc+3) issues at step kc and is
// consumed at step kc+2 -> ~2 full MFMA+barrier sections of flight, covering
// HBM latency (R19's depth-2 gave only ~1 section; dbuf itself was +6.6us).
__device__ __forceinline__ void g_mfma1(const short* cA, const short* cB,
                                        int wr, int wc, int lr, int qg,
                                        f32x4 (&acc)[4][4]){
  short8v af[4], bfr[4];
  #pragma unroll
  for (int m=0;m<4;m++){
    int row = wr*64 + m*16 + lr;
    af[m] = *(const short8v*)(cA + (row*4 + (qg ^ (row&3)))*8);
  }
  #pragma unroll
  for (int n=0;n<4;n++){
    int coln = wc*64 + n*16 + lr;
    bfr[n] = *(const short8v*)(cB + (coln*4 + (qg ^ (coln&3)))*8);
  }
  #pragma unroll
  for (int m=0;m<4;m++)
    #pragma unroll
    for (int n=0;n<4;n++)
      acc[m][n] = __builtin_amdgcn_mfma_f32_16x16x32_bf16(af[m], bfr[n], acc[m][n], 0, 0, 0);
}

__device__ __forceinline__ void g_cstore(short* __restrict__ C, int rowB,
                                         int wr, int wc, int lr, int qg,
                                         const f32x4 (&acc)[4][4]){
  #pragma unroll
  for (int m=0;m<4;m++){
    int crow = rowB + wr*64 + m*16 + qg*4;
    #pragma unroll
    for (int n=0;n<4;n++){
      int ccol = wc*64 + n*16 + lr;
      #pragma unroll
      for (int r=0;r<4;r++)
        C[(size_t)(crow + r)*256 + ccol] = f2bf(acc[m][n][r]);
    }
  }
}

// ---------------- fused: GEMM layer-0 (blocks 0..255) + CSR fill (256..1279) -
__global__ __launch_bounds__(512, 4) void k_gemm_x_fill(const float* __restrict__ X,
                                                        const short* __restrict__ Wt,
                                                        short* __restrict__ C,
                                                        const int* __restrict__ knn,
                                                        const void* __restrict__ maskp,
                                                        const int* __restrict__ flag,
                                                        int* __restrict__ fillptr,
                                                        int* __restrict__ col){
  __shared__ short lds[24576];   // 48KB: A0|A1|B0|B1
  if (blockIdx.x >= 256){
    int f = *flag;
    int fb = (int)blockIdx.x - 256;                      // 1024 blocks x 512
    int e  = ((fb & 7) << 16) + ((fb >> 3) << 9) + threadIdx.x;
    int node = e >> 4;
    int k    = (e & 15) + 1;
    int idx  = node*K1_ + k;
    if (mask_at(maskp, f, idx)){
      int b   = node >> 12;
      int dst = knn[idx] + (b<<12);
      int pos = atomicAdd(&fillptr[dst], 1);
      col[pos] = node;
    }
    return;
  }
  short* bufA[2] = { lds,        lds + 4096 };
  short* bufB[2] = { lds + 8192, lds + 16384 };
  int lb   = (int)(blockIdx.x & 7)*32 + (int)(blockIdx.x >> 3);  // XCD chunk
  int rowB = lb*128;

  int t    = threadIdx.x;
  int wave = t >> 6, lane = t & 63;
  int lr   = lane & 15, qg = lane >> 4;
  int wr   = wave >> 2, wc = wave & 3;

  f32x4 acc[4][4];
  #pragma unroll
  for (int m=0;m<4;m++)
    #pragma unroll
    for (int n=0;n<4;n++) acc[m][n] = (f32x4){0.f,0.f,0.f,0.f};

  int aRow = t >> 2, aCh = t & 3;
  int phA  = (aRow*4 + (aCh ^ (aRow&3)))*8;
  int bRow0 = t >> 2, bRow1 = (t >> 2) + 128, bCh = t & 3;
  int phB0 = (bRow0*4 + (bCh ^ (bRow0&3)))*8;
  int phB1 = (bRow1*4 + (bCh ^ (bRow1&3)))*8;
  const float* aBase  = X  + (size_t)(rowB+aRow)*512 + aCh*8;
  const short* bBase0 = Wt + (size_t)bRow0*256 + bCh*8;
  const short* bBase1 = Wt + (size_t)bRow1*256 + bCh*8;

  float4 ra0[2], ra1[2]; uint4 rb0[2], rb1[2];
  // k0 staged directly into buf0
  {
    float4 t0 = *(const float4*)aBase, t1 = *(const float4*)(aBase+4);
    uint4  w0 = *(const uint4*)bBase0, w1 = *(const uint4*)bBase1;
    uint4 cv;
    cv.x = pkbf(t0.x, t0.y); cv.y = pkbf(t0.z, t0.w);
    cv.z = pkbf(t1.x, t1.y); cv.w = pkbf(t1.z, t1.w);
    *(uint4*)(bufA[0] + phA) = cv;
    *(uint4*)(bufB[0] + phB0) = w0;
    *(uint4*)(bufB[0] + phB1) = w1;
  }
  // preload k1 -> set0, k2 -> set1
  ra0[0] = *(const float4*)(aBase + 32); ra1[0] = *(const float4*)(aBase + 36);
  rb0[0] = *(const uint4*)(bBase0 + 32); rb1[0] = *(const uint4*)(bBase1 + 32);
  ra0[1] = *(const float4*)(aBase + 64); ra1[1] = *(const float4*)(aBase + 68);
  rb0[1] = *(const uint4*)(bBase0 + 64); rb1[1] = *(const uint4*)(bBase1 + 64);
  __syncthreads();

  #pragma unroll
  for (int kc=0; kc<8; kc++){
    int s = kc & 1;
    if (kc < 7){                         // write set s (holds k(kc+1)) -> other buf
      short* dA = bufA[(kc+1)&1];
      short* dB = bufB[(kc+1)&1];
      uint4 cv;
      cv.x = pkbf(ra0[s].x, ra0[s].y); cv.y = pkbf(ra0[s].z, ra0[s].w);
      cv.z = pkbf(ra1[s].x, ra1[s].y); cv.w = pkbf(ra1[s].z, ra1[s].w);
      *(uint4*)(dA + phA) = cv;
      *(uint4*)(dB + phB0) = rb0[s];
      *(uint4*)(dB + phB1) = rb1[s];
    }
    if (kc < 5){                         // load k(kc+3) -> set s (2 steps of flight)
      const float* ap = aBase + (kc+3)*32;
      ra0[s] = *(const float4*)ap; ra1[s] = *(const float4*)(ap+4);
      rb0[s] = *(const uint4*)(bBase0 + (kc+3)*32);
      rb1[s] = *(const uint4*)(bBase1 + (kc+3)*32);
    }
    g_mfma1(bufA[s], bufB[s], wr, wc, lr, qg, acc);
    __syncthreads();
  }
  g_cstore(C, rowB, wr, wc, lr, qg, acc);
}

// layer 1 GEMM: stats fold + fused graph-norm + PReLU, depth-3 dbuf.
__global__ __launch_bounds__(512, 4) void k_gemm_n(const unsigned* __restrict__ BaggU,
                                                   const float* __restrict__ g,
                                                   const float* __restrict__ be,
                                                   const float* __restrict__ aP,
                                                   const float* __restrict__ partS,
                                                   const float* __restrict__ partQ,
                                                   const short* __restrict__ Wt,
                                                   short* __restrict__ C){
  __shared__ short lds[24576];
  float mean, inv;
  {
    double* sS = (double*)lds;            // bytes 0..4095 (512 doubles)
    double* sQ = (double*)(lds + 2048);   // bytes 4096..8191
    double a=0.0, b=0.0;
    for (int i=threadIdx.x; i<4096; i+=512){ a += (double)partS[i]; b += (double)partQ[i]; }
    sS[threadIdx.x]=a; sQ[threadIdx.x]=b;
    __syncthreads();
    for (int off=256; off>0; off>>=1){
      if ((int)threadIdx.x < off){ sS[threadIdx.x]+=sS[threadIdx.x+off]; sQ[threadIdx.x]+=sQ[threadIdx.x+off]; }
      __syncthreads();
    }
    if (threadIdx.x==0){
      double m   = sS[0] / (double)NP_;
      double var = sQ[0] / (double)NP_ - m*m;
      var = var > 0.0 ? var : 0.0;
      ((float*)lds)[0] = (float)m;
      ((float*)lds)[1] = (float)(1.0 / (sqrt(var) + (double)EPS_));
    }
    __syncthreads();
    mean = ((float*)lds)[0];
    inv  = ((float*)lds)[1];
    __syncthreads();
  }
  float a = aP[0];

  short* bufA[2] = { lds,        lds + 4096 };
  short* bufB[2] = { lds + 8192, lds + 16384 };
  int lb   = (int)(blockIdx.x & 7)*32 + (int)(blockIdx.x >> 3);
  int rowB = lb*128;

  int t    = threadIdx.x;
  int wave = t >> 6, lane = t & 63;
  int lr   = lane & 15, qg = lane >> 4;
  int wr   = wave >> 2, wc = wave & 3;

  f32x4 acc[4][4];
  #pragma unroll
  for (int m=0;m<4;m++)
    #pragma unroll
    for (int n=0;n<4;n++) acc[m][n] = (f32x4){0.f,0.f,0.f,0.f};

  int aRow = t >> 2, aCh = t & 3;
  int phA  = (aRow*4 + (aCh ^ (aRow&3)))*8;
  int bRow0 = t >> 2, bRow1 = (t >> 2) + 128, bCh = t & 3;
  int phB0 = (bRow0*4 + (bCh ^ (bRow0&3)))*8;
  int phB1 = (bRow1*4 + (bCh ^ (bRow1&3)))*8;
  const unsigned* aBase = BaggU + (size_t)(rowB+aRow)*128 + aCh*4;
  const short* bBase0 = Wt + (size_t)bRow0*256 + bCh*8;
  const short* bBase1 = Wt + (size_t)bRow1*256 + bCh*8;

  auto normWrite = [&](short* dA, uint4 raw, int kc){
    int c0 = kc*32 + aCh*8;
    float4 g0 = *(const float4*)&g[c0],  g1 = *(const float4*)&g[c0+4];
    float4 e0 = *(const float4*)&be[c0], e1 = *(const float4*)&be[c0+4];
    float v[8];
    unpack2(raw.x, v[0], v[1]); unpack2(raw.y, v[2], v[3]);
    unpack2(raw.z, v[4], v[5]); unpack2(raw.w, v[6], v[7]);
    float gg[8] = {g0.x,g0.y,g0.z,g0.w,g1.x,g1.y,g1.z,g1.w};
    float eb[8] = {e0.x,e0.y,e0.z,e0.w,e1.x,e1.y,e1.z,e1.w};
    float o[8];
    #pragma unroll
    for (int j=0;j<8;j++){
      float tt = gg[j]*((v[j]-mean)*inv) + eb[j];
      o[j] = tt>=0.f ? tt : a*tt;
    }
    uint4 cv;
    cv.x = pkbf(o[0],o[1]); cv.y = pkbf(o[2],o[3]);
    cv.z = pkbf(o[4],o[5]); cv.w = pkbf(o[6],o[7]);
    *(uint4*)(dA + phA) = cv;
  };

  uint4 ra[2], rb0[2], rb1[2];
  // k0 staged directly into buf0
  {
    uint4 t0 = *(const uint4*)aBase;
    uint4 w0 = *(const uint4*)bBase0, w1 = *(const uint4*)bBase1;
    normWrite(bufA[0], t0, 0);
    *(uint4*)(bufB[0] + phB0) = w0;
    *(uint4*)(bufB[0] + phB1) = w1;
  }
  // preload k1 -> set0, k2 -> set1
  ra[0]  = *(const uint4*)(aBase + 16);
  rb0[0] = *(const uint4*)(bBase0 + 32); rb1[0] = *(const uint4*)(bBase1 + 32);
  ra[1]  = *(const uint4*)(aBase + 32);
  rb0[1] = *(const uint4*)(bBase0 + 64); rb1[1] = *(const uint4*)(bBase1 + 64);
  __syncthreads();

  #pragma unroll
  for (int kc=0; kc<8; kc++){
    int s = kc & 1;
    if (kc < 7){
      short* dA = bufA[(kc+1)&1];
      short* dB = bufB[(kc+1)&1];
      normWrite(dA, ra[s], kc+1);
      *(uint4*)(dB + phB0) = rb0[s];
      *(uint4*)(dB + phB1) = rb1[s];
    }
    if (kc < 5){
      ra[s]  = *(const uint4*)(aBase + (kc+3)*16);
      rb0[s] = *(const uint4*)(bBase0 + (kc+3)*32);
      rb1[s] = *(const uint4*)(bBase1 + (kc+3)*32);
    }
    g_mfma1(bufA[s], bufB[s], wr, wc, lr, qg, acc);
    __syncthreads();
  }
  g_cstore(C, rowB, wr, wc, lr, qg, acc);
}

// ---------------- aggregation: 32 lanes/node, parallel gather pipeline ------
__global__ __launch_bounds__(256) void k_agg(const short* __restrict__ Ab,
    const int* __restrict__ rowptr, const int* __restrict__ col,
    const float* __restrict__ dinv, const float* __restrict__ bvec,
    unsigned* __restrict__ outU, float* __restrict__ partS, float* __restrict__ partQ){
  int bid  = (int)(blockIdx.x & 7) * 512 + (int)(blockIdx.x >> 3);  // XCD swizzle
  int node = bid*8 + (threadIdx.x >> 5);
  int sub  = threadIdx.x & 31;
  int c0   = sub*8;
  float dv = dinv[node];

  float acc[8];
  {
    short8v s = *(const short8v*)&Ab[(size_t)node*256 + c0];
    #pragma unroll
    for (int i=0;i<8;i++) acc[i] = dv * bf2f(s[i]);
  }
  int j0 = rowptr[node], j1 = rowptr[node+1];
  for (int base=j0; base<j1; base+=32){
    int n = j1 - base; n = n < 32 ? n : 32;
    int   myc = (sub < n) ? col[base+sub] : 0;
    float myd = (sub < n) ? dinv[myc]     : 0.f;
    for (int j=0;j<n;j++){
      int   s  = __shfl(myc, j, 32);
      float ds = __shfl(myd, j, 32);
      short8v nb = *(const short8v*)&Ab[(size_t)s*256 + c0];
      #pragma unroll
      for (int i=0;i<8;i++) acc[i] += ds * bf2f(nb[i]);
    }
  }
  float sum=0.f, sq=0.f;
  float o[8];
  #pragma unroll
  for (int i=0;i<8;i++){
    float v = dv*acc[i] + bvec[c0+i];
    o[i] = v;
    sum += v; sq += v*v;
  }
  uint4 ov;
  ov.x = pkbf(o[0],o[1]); ov.y = pkbf(o[2],o[3]);
  ov.z = pkbf(o[4],o[5]); ov.w = pkbf(o[6],o[7]);
  *(uint4*)&outU[(size_t)node*128 + sub*4] = ov;

  #pragma unroll
  for (int off=16; off>0; off>>=1){
    sum += __shfl_down(sum, off, 32);
    sq  += __shfl_down(sq,  off, 32);
  }
  __shared__ float ls1[8], ls2[8];
  if (sub==0){ ls1[threadIdx.x>>5]=sum; ls2[threadIdx.x>>5]=sq; }
  __syncthreads();
  if (threadIdx.x==0){
    float a=0.f, b=0.f;
    #pragma unroll
    for (int i=0;i<8;i++){ a+=ls1[i]; b+=ls2[i]; }
    partS[bid]=a; partQ[bid]=b;
  }
}

// ---------------- final norm + prelu (stats fold, grid-stride x4) -----------
__global__ __launch_bounds__(256) void k_norm_f32(const unsigned* __restrict__ inU,
    const float* __restrict__ g, const float* __restrict__ be,
    const float* __restrict__ aP, const float* __restrict__ partS,
    const float* __restrict__ partQ, float* __restrict__ out){
  __shared__ double sS[256], sQ[256];
  __shared__ float s_mean, s_inv;
  {
    double a=0.0, b=0.0;
    for (int i=threadIdx.x; i<4096; i+=256){ a += (double)partS[i]; b += (double)partQ[i]; }
    sS[threadIdx.x]=a; sQ[threadIdx.x]=b;
    __syncthreads();
    for (int off=128; off>0; off>>=1){
      if ((int)threadIdx.x < off){ sS[threadIdx.x]+=sS[threadIdx.x+off]; sQ[threadIdx.x]+=sQ[threadIdx.x+off]; }
      __syncthreads();
    }
    if (threadIdx.x==0){
      double m   = sS[0] / (double)NP_;
      double var = sQ[0] / (double)NP_ - m*m;
      var = var > 0.0 ? var : 0.0;
      s_mean = (float)m;
      s_inv  = (float)(1.0 / (sqrt(var) + (double)EPS_));
    }
    __syncthreads();
  }
  float mean = s_mean, inv = s_inv, a = aP[0];
  #pragma unroll
  for (int it=0; it<4; it++){
    int gid   = it*(1024*256) + blockIdx.x*256 + threadIdx.x;
    int base8 = gid*8;
    int c0    = base8 & (D_-1);
    uint4 vin = *(const uint4*)&inU[gid*4];
    float4 g0 = *(const float4*)&g[c0],  g1 = *(const float4*)&g[c0+4];
    float4 e0 = *(const float4*)&be[c0], e1 = *(const float4*)&be[c0+4];
    float v[8];
    unpack2(vin.x, v[0], v[1]); unpack2(vin.y, v[2], v[3]);
    unpack2(vin.z, v[4], v[5]); unpack2(vin.w, v[6], v[7]);
    float gg[8] = {g0.x,g0.y,g0.z,g0.w,g1.x,g1.y,g1.z,g1.w};
    float eb[8] = {e0.x,e0.y,e0.z,e0.w,e1.x,e1.y,e1.z,e1.w};
    f32x4 o0, o1;
    #pragma unroll
    for (int i=0;i<8;i++){
      float tt = gg[i]*((v[i]-mean)*inv) + eb[i];
      tt = tt>=0.f ? tt : a*tt;
      if (i<4) o0[i] = tt; else o1[i-4] = tt;
    }
    *(f32x4*)&out[base8]     = o0;
    *(f32x4*)&out[base8 + 4] = o1;
  }
}

// ---------------- launch ----------------

extern "C" void kernel_launch(void* const* d_in, const int* in_sizes, int n_in,
                              void* d_out, int out_size, void* d_ws, size_t ws_size,
                              hipStream_t stream){
  const float* x    = (const float*)d_in[0];
  const int*   knn  = (const int*)  d_in[1];
  const void*  mask =               d_in[2];
  const float* W0   = (const float*)d_in[3];
  const float* b0   = (const float*)d_in[4];
  const float* g0   = (const float*)d_in[5];
  const float* be0  = (const float*)d_in[6];
  const float* a0   = (const float*)d_in[7];
  const float* W1   = (const float*)d_in[8];
  const float* b1   = (const float*)d_in[9];
  const float* g1   = (const float*)d_in[10];
  const float* be1  = (const float*)d_in[11];
  const float* a1   = (const float*)d_in[12];
  float* out = (float*)d_out;

  char* w = (char*)d_ws;
  size_t off = 0;
  auto alloc = [&](size_t bytes)->void*{
    void* p = w + off; off = (off + bytes + 255) & ~(size_t)255; return p;
  };
  int*      degcnt  = (int*)     alloc(NT_*4);
  int*      rowptr  = (int*)     alloc((NT_+1)*4);
  int*      fillptr = (int*)     alloc(NT_*4);
  int*      col     = (int*)     alloc(E16_*4);
  float*    dinv    = (float*)   alloc(NT_*4);
  float*    partS   = (float*)   alloc(4096*4);
  float*    partQ   = (float*)   alloc(4096*4);
  int*      flag    = (int*)     alloc(4);
  short*    Ab      = (short*)   alloc((size_t)NP_*2);   // gemm output (bf16)
  unsigned* Bagg    = (unsigned*)alloc((size_t)NP_*2);   // agg output (bf16 pairs)
  short*    Wt0     = (short*)   alloc(256*256*2);
  short*    Wt1     = (short*)   alloc(256*256*2);

  // prep (weights + degcnt zero + detect) -> deg -> scan
  hipLaunchKernelGGL(k_prep,  dim3(256),      dim3(256), 0, stream, W0, W1, Wt0, Wt1,
                     degcnt, (const unsigned int*)mask, flag);
  hipLaunchKernelGGL(k_deg,   dim3(E16_/256), dim3(256), 0, stream, knn, mask, flag, degcnt);
  hipLaunchKernelGGL(k_scan,  dim3(1),        dim3(1024),0, stream, degcnt, rowptr, fillptr, dinv);

  // layer 0: depth-3 dbuf gemm + XCD-batch-local CSR fill
  hipLaunchKernelGGL(k_gemm_x_fill, dim3(1280), dim3(512), 0, stream, x, Wt0, Ab,
                     knn, mask, flag, fillptr, col);
  hipLaunchKernelGGL(k_agg,    dim3(NT_/8),   dim3(256), 0, stream, Ab, rowptr, col, dinv, b0, Bagg, partS, partQ);

  // layer 1 (stats + norm0 + prelu folded into gemm staging)
  hipLaunchKernelGGL(k_gemm_n, dim3(256),     dim3(512), 0, stream, Bagg, g0, be0, a0,
                     partS, partQ, Wt1, Ab);
  hipLaunchKernelGGL(k_agg,    dim3(NT_/8),   dim3(256), 0, stream, Ab, rowptr, col, dinv, b1, Bagg, partS, partQ);
  hipLaunchKernelGGL(k_norm_f32, dim3(1024),  dim3(256), 0, stream, Bagg, g1, be1, a1,
                     partS, partQ, out);
}

// Round 21
// 150.607 us; speedup vs baseline: 1.0427x; 1.0427x over previous
//
#include <hip/hip_runtime.h>
#include <hip/hip_bf16.h>
#include <stdint.h>

#define B_   8
#define N_   4096
#define K1_  17
#define D_   256
#define NT_  (B_*N_)          // 32768
#define E16_ (NT_*16)         // 524288
#define NP_  (NT_*D_)         // 8388608
#define EPS_ 1e-5f

typedef __attribute__((ext_vector_type(8))) short short8v;  // 8 bf16 (4 VGPR)
typedef __attribute__((ext_vector_type(4))) float f32x4;

// f32 -> bf16 RNE, pure C
__device__ __forceinline__ unsigned short f2bfu(float f){
  unsigned u = __float_as_uint(f);
  unsigned r = (u + 0x7FFFu + ((u>>16)&1u)) >> 16;
  return (unsigned short)r;
}
__device__ __forceinline__ short f2bf(float f){ return (short)f2bfu(f); }
__device__ __forceinline__ unsigned pkbf(float lo, float hi){
  return (unsigned)f2bfu(lo) | ((unsigned)f2bfu(hi) << 16);
}
__device__ __forceinline__ float bf2f(short s){
  return __uint_as_float(((unsigned)(unsigned short)s) << 16);
}
__device__ __forceinline__ void unpack2(unsigned u, float& lo, float& hi){
  lo = __uint_as_float(u << 16);
  hi = __uint_as_float(u & 0xFFFF0000u);
}

// ---------------- prep: weight transpose + degcnt zero + mask detect --------
__global__ __launch_bounds__(256) void k_prep(const float* __restrict__ W0,
                                              const float* __restrict__ W1,
                                              short* __restrict__ Wt0,
                                              short* __restrict__ Wt1,
                                              int* __restrict__ degcnt,
                                              const unsigned int* __restrict__ mw,
                                              int* __restrict__ flag){
  if (blockIdx.x < 128){
    const float* W  = (blockIdx.x & 1) ? W1  : W0;
    short*       Wt = (blockIdx.x & 1) ? Wt1 : Wt0;
    int tile = blockIdx.x >> 1;
    int ti = tile >> 3, tj = tile & 7;
    __shared__ float sm[32][33];
    int r = threadIdx.x >> 5, c = threadIdx.x & 31;
    #pragma unroll
    for (int i=0;i<4;i++)
      sm[r + i*8][c] = W[(ti*32 + r + i*8)*256 + tj*32 + c];
    __syncthreads();
    #pragma unroll
    for (int i=0;i<4;i++){
      int rr = r + i*8;
      Wt[(size_t)(tj*32 + rr)*256 + ti*32 + c] = f2bf(sm[c][rr]);
    }
  } else {
    int ib = blockIdx.x - 128;
    int i  = ib*256 + threadIdx.x;
    degcnt[i] = 0;
    if (ib == 0){
      __shared__ int s_int, s_f32;
      if (threadIdx.x==0){ s_int=1; s_f32=1; }
      __syncthreads();
      int bad_i=0, bad_f=0;
      #pragma unroll
      for (int j=0;j<4;j++){
        unsigned w = mw[threadIdx.x*4 + j];
        if (!(w==0u || w==1u))          bad_i=1;
        if (!(w==0u || w==0x3F800000u)) bad_f=1;
      }
      if (bad_i) atomicAnd(&s_int, 0);
      if (bad_f) atomicAnd(&s_f32, 0);
      __syncthreads();
      if (threadIdx.x==0) *flag = s_int ? 0 : (s_f32 ? 1 : 2);
    }
  }
}

__device__ __forceinline__ bool mask_at(const void* maskp, int f, int idx){
  if (f==0) return ((const int*)maskp)[idx] != 0;
  if (f==1) return ((const float*)maskp)[idx] != 0.0f;
  return ((const unsigned char*)maskp)[idx] != 0;
}

// deg: XCD-batch-swizzled edge ranges (batch b -> XCD b; local-L2 atomics)
__global__ void k_deg(const int* __restrict__ knn, const void* __restrict__ maskp,
                      const int* __restrict__ flag, int* __restrict__ degcnt){
  int f = *flag;
  int bid = blockIdx.x;                                  // 2048 blocks x 256
  int e = ((bid & 7) << 16) + ((bid >> 3) << 8) + threadIdx.x;
  int node = e >> 4;
  int k    = (e & 15) + 1;
  int idx  = node*K1_ + k;
  if (mask_at(maskp, f, idx)){
    int b   = node >> 12;
    int dst = knn[idx] + (b<<12);
    atomicAdd(&degcnt[dst], 1);
  }
}

// wave-shfl scan: 1024 thr = 16 waves; 6 shfl steps + ONE barrier
__global__ void k_scan(const int* __restrict__ degcnt, int* __restrict__ rowptr,
                       int* __restrict__ fillptr, float* __restrict__ dinv){
  __shared__ int wsum[16];
  int t = threadIdx.x;
  int lane = t & 63, wid = t >> 6;
  int base = t*32;
  int loc[32]; int tot = 0;
  #pragma unroll
  for (int i=0;i<32;i++){ loc[i] = degcnt[base+i]; tot += loc[i]; }
  int inc = tot;
  #pragma unroll
  for (int off=1; off<64; off<<=1){
    int v = __shfl_up(inc, off, 64);
    if (lane >= off) inc += v;
  }
  if (lane == 63) wsum[wid] = inc;
  __syncthreads();
  int woff = 0;
  #pragma unroll
  for (int i=0;i<16;i++) if (i < wid) woff += wsum[i];
  int run = woff + inc - tot;          // exclusive prefix
  #pragma unroll
  for (int i=0;i<32;i++){
    int v = base+i;
    rowptr[v]  = run;
    fillptr[v] = run;
    dinv[v]    = rsqrtf((float)loc[i] + 1.0f);
    run += loc[i];
  }
  if (t==1023) rowptr[NT_] = run;
}

// ---------------- double-buffered MFMA GEMM (tile 128x256, BK=32) -----------
// 512 thr = 8 waves (2x4). 8 K-steps, ONE barrier each: ds_write of step
// kc+1 targets the other buffer (overlaps step kc's MFMA); global loads are
// issued 2 steps ahead. Depth-2 is the measured optimum (R18 d1=157.5,
// R19 d2=150.9, R20 d3=157.0).
// LDS: 2 x (A 8KB + B 16KB) = 48KB. Chunk swizzle ch^(row&3), both sides.
__device__ __forceinline__ void g_mfma1(const short* cA, const short* cB,
                                        int wr, int wc, int lr, int qg,
                                        f32x4 (&acc)[4][4]){
  short8v af[4], bfr[4];
  #pragma unroll
  for (int m=0;m<4;m++){
    int row = wr*64 + m*16 + lr;
    af[m] = *(const short8v*)(cA + (row*4 + (qg ^ (row&3)))*8);
  }
  #pragma unroll
  for (int n=0;n<4;n++){
    int coln = wc*64 + n*16 + lr;
    bfr[n] = *(const short8v*)(cB + (coln*4 + (qg ^ (coln&3)))*8);
  }
  #pragma unroll
  for (int m=0;m<4;m++)
    #pragma unroll
    for (int n=0;n<4;n++)
      acc[m][n] = __builtin_amdgcn_mfma_f32_16x16x32_bf16(af[m], bfr[n], acc[m][n], 0, 0, 0);
}

__device__ __forceinline__ void g_cstore(short* __restrict__ C, int rowB,
                                         int wr, int wc, int lr, int qg,
                                         const f32x4 (&acc)[4][4]){
  #pragma unroll
  for (int m=0;m<4;m++){
    int crow = rowB + wr*64 + m*16 + qg*4;
    #pragma unroll
    for (int n=0;n<4;n++){
      int ccol = wc*64 + n*16 + lr;
      #pragma unroll
      for (int r=0;r<4;r++)
        C[(size_t)(crow + r)*256 + ccol] = f2bf(acc[m][n][r]);
    }
  }
}

// ---------------- fused: GEMM layer-0 (blocks 0..255) + CSR fill (256..1279) -
__global__ __launch_bounds__(512, 4) void k_gemm_x_fill(const float* __restrict__ X,
                                                        const short* __restrict__ Wt,
                                                        short* __restrict__ C,
                                                        const int* __restrict__ knn,
                                                        const void* __restrict__ maskp,
                                                        const int* __restrict__ flag,
                                                        int* __restrict__ fillptr,
                                                        int* __restrict__ col){
  __shared__ short lds[24576];   // 48KB: A0|A1|B0|B1
  if (blockIdx.x >= 256){
    int f = *flag;
    int fb = (int)blockIdx.x - 256;                      // 1024 blocks x 512
    int e  = ((fb & 7) << 16) + ((fb >> 3) << 9) + threadIdx.x;
    int node = e >> 4;
    int k    = (e & 15) + 1;
    int idx  = node*K1_ + k;
    if (mask_at(maskp, f, idx)){
      int b   = node >> 12;
      int dst = knn[idx] + (b<<12);
      int pos = atomicAdd(&fillptr[dst], 1);
      col[pos] = node;
    }
    return;
  }
  short* bufA[2] = { lds,        lds + 4096 };
  short* bufB[2] = { lds + 8192, lds + 16384 };
  int lb   = (int)(blockIdx.x & 7)*32 + (int)(blockIdx.x >> 3);  // XCD chunk
  int rowB = lb*128;

  int t    = threadIdx.x;
  int wave = t >> 6, lane = t & 63;
  int lr   = lane & 15, qg = lane >> 4;
  int wr   = wave >> 2, wc = wave & 3;

  f32x4 acc[4][4];
  #pragma unroll
  for (int m=0;m<4;m++)
    #pragma unroll
    for (int n=0;n<4;n++) acc[m][n] = (f32x4){0.f,0.f,0.f,0.f};

  // A: 512 slots (128 rows x 4 chunks), 1/thread. B: 1024 slots, 2/thread.
  int aRow = t >> 2, aCh = t & 3;
  int phA  = (aRow*4 + (aCh ^ (aRow&3)))*8;
  int bRow0 = t >> 2, bRow1 = (t >> 2) + 128, bCh = t & 3;
  int phB0 = (bRow0*4 + (bCh ^ (bRow0&3)))*8;
  int phB1 = (bRow1*4 + (bCh ^ (bRow1&3)))*8;
  const float* aBase  = X  + (size_t)(rowB+aRow)*512 + aCh*8;
  const short* bBase0 = Wt + (size_t)bRow0*256 + bCh*8;
  const short* bBase1 = Wt + (size_t)bRow1*256 + bCh*8;

  float4 ra0, ra1; uint4 rb0, rb1;
  // k0 -> buf0
  ra0 = *(const float4*)aBase; ra1 = *(const float4*)(aBase+4);
  rb0 = *(const uint4*)bBase0; rb1 = *(const uint4*)bBase1;
  {
    uint4 cv;
    cv.x = pkbf(ra0.x, ra0.y); cv.y = pkbf(ra0.z, ra0.w);
    cv.z = pkbf(ra1.x, ra1.y); cv.w = pkbf(ra1.z, ra1.w);
    *(uint4*)(bufA[0] + phA) = cv;
    *(uint4*)(bufB[0] + phB0) = rb0;
    *(uint4*)(bufB[0] + phB1) = rb1;
  }
  // load k1
  ra0 = *(const float4*)(aBase + 32); ra1 = *(const float4*)(aBase + 36);
  rb0 = *(const uint4*)(bBase0 + 32); rb1 = *(const uint4*)(bBase1 + 32);
  __syncthreads();

  #pragma unroll
  for (int kc=0; kc<8; kc++){
    if (kc < 7){                         // write regs(kc+1) -> other buffer
      short* dA = bufA[(kc+1)&1];
      short* dB = bufB[(kc+1)&1];
      uint4 cv;
      cv.x = pkbf(ra0.x, ra0.y); cv.y = pkbf(ra0.z, ra0.w);
      cv.z = pkbf(ra1.x, ra1.y); cv.w = pkbf(ra1.z, ra1.w);
      *(uint4*)(dA + phA) = cv;
      *(uint4*)(dB + phB0) = rb0;
      *(uint4*)(dB + phB1) = rb1;
    }
    if (kc < 6){                         // issue loads for kc+2
      const float* ap = aBase + (kc+2)*32;
      ra0 = *(const float4*)ap; ra1 = *(const float4*)(ap+4);
      rb0 = *(const uint4*)(bBase0 + (kc+2)*32);
      rb1 = *(const uint4*)(bBase1 + (kc+2)*32);
    }
    g_mfma1(bufA[kc&1], bufB[kc&1], wr, wc, lr, qg, acc);
    __syncthreads();
  }
  g_cstore(C, rowB, wr, wc, lr, qg, acc);
}

// layer 1 GEMM: stats fold + fused graph-norm + PReLU, double-buffered.
__global__ __launch_bounds__(512, 4) void k_gemm_n(const unsigned* __restrict__ BaggU,
                                                   const float* __restrict__ g,
                                                   const float* __restrict__ be,
                                                   const float* __restrict__ aP,
                                                   const float* __restrict__ partS,
                                                   const float* __restrict__ partQ,
                                                   const short* __restrict__ Wt,
                                                   short* __restrict__ C){
  __shared__ short lds[24576];
  float mean, inv;
  {
    double* sS = (double*)lds;            // bytes 0..4095 (512 doubles)
    double* sQ = (double*)(lds + 2048);   // bytes 4096..8191
    double a=0.0, b=0.0;
    for (int i=threadIdx.x; i<4096; i+=512){ a += (double)partS[i]; b += (double)partQ[i]; }
    sS[threadIdx.x]=a; sQ[threadIdx.x]=b;
    __syncthreads();
    for (int off=256; off>0; off>>=1){
      if ((int)threadIdx.x < off){ sS[threadIdx.x]+=sS[threadIdx.x+off]; sQ[threadIdx.x]+=sQ[threadIdx.x+off]; }
      __syncthreads();
    }
    if (threadIdx.x==0){
      double m   = sS[0] / (double)NP_;
      double var = sQ[0] / (double)NP_ - m*m;
      var = var > 0.0 ? var : 0.0;
      ((float*)lds)[0] = (float)m;
      ((float*)lds)[1] = (float)(1.0 / (sqrt(var) + (double)EPS_));
    }
    __syncthreads();
    mean = ((float*)lds)[0];
    inv  = ((float*)lds)[1];
    __syncthreads();
  }
  float a = aP[0];

  short* bufA[2] = { lds,        lds + 4096 };
  short* bufB[2] = { lds + 8192, lds + 16384 };
  int lb   = (int)(blockIdx.x & 7)*32 + (int)(blockIdx.x >> 3);
  int rowB = lb*128;

  int t    = threadIdx.x;
  int wave = t >> 6, lane = t & 63;
  int lr   = lane & 15, qg = lane >> 4;
  int wr   = wave >> 2, wc = wave & 3;

  f32x4 acc[4][4];
  #pragma unroll
  for (int m=0;m<4;m++)
    #pragma unroll
    for (int n=0;n<4;n++) acc[m][n] = (f32x4){0.f,0.f,0.f,0.f};

  int aRow = t >> 2, aCh = t & 3;
  int phA  = (aRow*4 + (aCh ^ (aRow&3)))*8;
  int bRow0 = t >> 2, bRow1 = (t >> 2) + 128, bCh = t & 3;
  int phB0 = (bRow0*4 + (bCh ^ (bRow0&3)))*8;
  int phB1 = (bRow1*4 + (bCh ^ (bRow1&3)))*8;
  const unsigned* aBase = BaggU + (size_t)(rowB+aRow)*128 + aCh*4;
  const short* bBase0 = Wt + (size_t)bRow0*256 + bCh*8;
  const short* bBase1 = Wt + (size_t)bRow1*256 + bCh*8;

  // norm+prelu applied at ds_write time; coeffs per step kc: c0 = kc*32+aCh*8
  auto normWrite = [&](short* dA, uint4 raw, int kc){
    int c0 = kc*32 + aCh*8;
    float4 g0 = *(const float4*)&g[c0],  g1 = *(const float4*)&g[c0+4];
    float4 e0 = *(const float4*)&be[c0], e1 = *(const float4*)&be[c0+4];
    float v[8];
    unpack2(raw.x, v[0], v[1]); unpack2(raw.y, v[2], v[3]);
    unpack2(raw.z, v[4], v[5]); unpack2(raw.w, v[6], v[7]);
    float gg[8] = {g0.x,g0.y,g0.z,g0.w,g1.x,g1.y,g1.z,g1.w};
    float eb[8] = {e0.x,e0.y,e0.z,e0.w,e1.x,e1.y,e1.z,e1.w};
    float o[8];
    #pragma unroll
    for (int j=0;j<8;j++){
      float tt = gg[j]*((v[j]-mean)*inv) + eb[j];
      o[j] = tt>=0.f ? tt : a*tt;
    }
    uint4 cv;
    cv.x = pkbf(o[0],o[1]); cv.y = pkbf(o[2],o[3]);
    cv.z = pkbf(o[4],o[5]); cv.w = pkbf(o[6],o[7]);
    *(uint4*)(dA + phA) = cv;
  };

  uint4 ra, rb0, rb1;
  // k0 -> buf0
  ra  = *(const uint4*)aBase;
  rb0 = *(const uint4*)bBase0; rb1 = *(const uint4*)bBase1;
  normWrite(bufA[0], ra, 0);
  *(uint4*)(bufB[0] + phB0) = rb0;
  *(uint4*)(bufB[0] + phB1) = rb1;
  // load k1
  ra  = *(const uint4*)(aBase + 16);
  rb0 = *(const uint4*)(bBase0 + 32); rb1 = *(const uint4*)(bBase1 + 32);
  __syncthreads();

  #pragma unroll
  for (int kc=0; kc<8; kc++){
    if (kc < 7){
      short* dA = bufA[(kc+1)&1];
      short* dB = bufB[(kc+1)&1];
      normWrite(dA, ra, kc+1);
      *(uint4*)(dB + phB0) = rb0;
      *(uint4*)(dB + phB1) = rb1;
    }
    if (kc < 6){
      ra  = *(const uint4*)(aBase + (kc+2)*16);
      rb0 = *(const uint4*)(bBase0 + (kc+2)*32);
      rb1 = *(const uint4*)(bBase1 + (kc+2)*32);
    }
    g_mfma1(bufA[kc&1], bufB[kc&1], wr, wc, lr, qg, acc);
    __syncthreads();
  }
  g_cstore(C, rowB, wr, wc, lr, qg, acc);
}

// ---------------- aggregation: 32 lanes/node, parallel gather pipeline ------
__global__ __launch_bounds__(256) void k_agg(const short* __restrict__ Ab,
    const int* __restrict__ rowptr, const int* __restrict__ col,
    const float* __restrict__ dinv, const float* __restrict__ bvec,
    unsigned* __restrict__ outU, float* __restrict__ partS, float* __restrict__ partQ){
  int bid  = (int)(blockIdx.x & 7) * 512 + (int)(blockIdx.x >> 3);  // XCD swizzle
  int node = bid*8 + (threadIdx.x >> 5);
  int sub  = threadIdx.x & 31;
  int c0   = sub*8;
  float dv = dinv[node];

  float acc[8];
  {
    short8v s = *(const short8v*)&Ab[(size_t)node*256 + c0];
    #pragma unroll
    for (int i=0;i<8;i++) acc[i] = dv * bf2f(s[i]);
  }
  int j0 = rowptr[node], j1 = rowptr[node+1];
  for (int base=j0; base<j1; base+=32){
    int n = j1 - base; n = n < 32 ? n : 32;
    int   myc = (sub < n) ? col[base+sub] : 0;
    float myd = (sub < n) ? dinv[myc]     : 0.f;
    for (int j=0;j<n;j++){
      int   s  = __shfl(myc, j, 32);
      float ds = __shfl(myd, j, 32);
      short8v nb = *(const short8v*)&Ab[(size_t)s*256 + c0];
      #pragma unroll
      for (int i=0;i<8;i++) acc[i] += ds * bf2f(nb[i]);
    }
  }
  float sum=0.f, sq=0.f;
  float o[8];
  #pragma unroll
  for (int i=0;i<8;i++){
    float v = dv*acc[i] + bvec[c0+i];
    o[i] = v;
    sum += v; sq += v*v;
  }
  uint4 ov;
  ov.x = pkbf(o[0],o[1]); ov.y = pkbf(o[2],o[3]);
  ov.z = pkbf(o[4],o[5]); ov.w = pkbf(o[6],o[7]);
  *(uint4*)&outU[(size_t)node*128 + sub*4] = ov;

  #pragma unroll
  for (int off=16; off>0; off>>=1){
    sum += __shfl_down(sum, off, 32);
    sq  += __shfl_down(sq,  off, 32);
  }
  __shared__ float ls1[8], ls2[8];
  if (sub==0){ ls1[threadIdx.x>>5]=sum; ls2[threadIdx.x>>5]=sq; }
  __syncthreads();
  if (threadIdx.x==0){
    float a=0.f, b=0.f;
    #pragma unroll
    for (int i=0;i<8;i++){ a+=ls1[i]; b+=ls2[i]; }
    partS[bid]=a; partQ[bid]=b;
  }
}

// ---------------- final norm + prelu (stats fold, grid-stride x4) -----------
__global__ __launch_bounds__(256) void k_norm_f32(const unsigned* __restrict__ inU,
    const float* __restrict__ g, const float* __restrict__ be,
    const float* __restrict__ aP, const float* __restrict__ partS,
    const float* __restrict__ partQ, float* __restrict__ out){
  __shared__ double sS[256], sQ[256];
  __shared__ float s_mean, s_inv;
  {
    double a=0.0, b=0.0;
    for (int i=threadIdx.x; i<4096; i+=256){ a += (double)partS[i]; b += (double)partQ[i]; }
    sS[threadIdx.x]=a; sQ[threadIdx.x]=b;
    __syncthreads();
    for (int off=128; off>0; off>>=1){
      if ((int)threadIdx.x < off){ sS[threadIdx.x]+=sS[threadIdx.x+off]; sQ[threadIdx.x]+=sQ[threadIdx.x+off]; }
      __syncthreads();
    }
    if (threadIdx.x==0){
      double m   = sS[0] / (double)NP_;
      double var = sQ[0] / (double)NP_ - m*m;
      var = var > 0.0 ? var : 0.0;
      s_mean = (float)m;
      s_inv  = (float)(1.0 / (sqrt(var) + (double)EPS_));
    }
    __syncthreads();
  }
  float mean = s_mean, inv = s_inv, a = aP[0];
  #pragma unroll
  for (int it=0; it<4; it++){
    int gid   = it*(1024*256) + blockIdx.x*256 + threadIdx.x;
    int base8 = gid*8;
    int c0    = base8 & (D_-1);
    uint4 vin = *(const uint4*)&inU[gid*4];
    float4 g0 = *(const float4*)&g[c0],  g1 = *(const float4*)&g[c0+4];
    float4 e0 = *(const float4*)&be[c0], e1 = *(const float4*)&be[c0+4];
    float v[8];
    unpack2(vin.x, v[0], v[1]); unpack2(vin.y, v[2], v[3]);
    unpack2(vin.z, v[4], v[5]); unpack2(vin.w, v[6], v[7]);
    float gg[8] = {g0.x,g0.y,g0.z,g0.w,g1.x,g1.y,g1.z,g1.w};
    float eb[8] = {e0.x,e0.y,e0.z,e0.w,e1.x,e1.y,e1.z,e1.w};
    f32x4 o0, o1;
    #pragma unroll
    for (int i=0;i<8;i++){
      float tt = gg[i]*((v[i]-mean)*inv) + eb[i];
      tt = tt>=0.f ? tt : a*tt;
      if (i<4) o0[i] = tt; else o1[i-4] = tt;
    }
    *(f32x4*)&out[base8]     = o0;
    *(f32x4*)&out[base8 + 4] = o1;
  }
}

// ---------------- launch ----------------

extern "C" void kernel_launch(void* const* d_in, const int* in_sizes, int n_in,
                              void* d_out, int out_size, void* d_ws, size_t ws_size,
                              hipStream_t stream){
  const float* x    = (const float*)d_in[0];
  const int*   knn  = (const int*)  d_in[1];
  const void*  mask =               d_in[2];
  const float* W0   = (const float*)d_in[3];
  const float* b0   = (const float*)d_in[4];
  const float* g0   = (const float*)d_in[5];
  const float* be0  = (const float*)d_in[6];
  const float* a0   = (const float*)d_in[7];
  const float* W1   = (const float*)d_in[8];
  const float* b1   = (const float*)d_in[9];
  const float* g1   = (const float*)d_in[10];
  const float* be1  = (const float*)d_in[11];
  const float* a1   = (const float*)d_in[12];
  float* out = (float*)d_out;

  char* w = (char*)d_ws;
  size_t off = 0;
  auto alloc = [&](size_t bytes)->void*{
    void* p = w + off; off = (off + bytes + 255) & ~(size_t)255; return p;
  };
  int*      degcnt  = (int*)     alloc(NT_*4);
  int*      rowptr  = (int*)     alloc((NT_+1)*4);
  int*      fillptr = (int*)     alloc(NT_*4);
  int*      col     = (int*)     alloc(E16_*4);
  float*    dinv    = (float*)   alloc(NT_*4);
  float*    partS   = (float*)   alloc(4096*4);
  float*    partQ   = (float*)   alloc(4096*4);
  int*      flag    = (int*)     alloc(4);
  short*    Ab      = (short*)   alloc((size_t)NP_*2);   // gemm output (bf16)
  unsigned* Bagg    = (unsigned*)alloc((size_t)NP_*2);   // agg output (bf16 pairs)
  short*    Wt0     = (short*)   alloc(256*256*2);
  short*    Wt1     = (short*)   alloc(256*256*2);

  // prep (weights + degcnt zero + detect) -> deg -> scan
  hipLaunchKernelGGL(k_prep,  dim3(256),      dim3(256), 0, stream, W0, W1, Wt0, Wt1,
                     degcnt, (const unsigned int*)mask, flag);
  hipLaunchKernelGGL(k_deg,   dim3(E16_/256), dim3(256), 0, stream, knn, mask, flag, degcnt);
  hipLaunchKernelGGL(k_scan,  dim3(1),        dim3(1024),0, stream, degcnt, rowptr, fillptr, dinv);

  // layer 0: dbuf gemm (X read once) + XCD-batch-local CSR fill
  hipLaunchKernelGGL(k_gemm_x_fill, dim3(1280), dim3(512), 0, stream, x, Wt0, Ab,
                     knn, mask, flag, fillptr, col);
  hipLaunchKernelGGL(k_agg,    dim3(NT_/8),   dim3(256), 0, stream, Ab, rowptr, col, dinv, b0, Bagg, partS, partQ);

  // layer 1 (stats + norm0 + prelu folded into gemm staging)
  hipLaunchKernelGGL(k_gemm_n, dim3(256),     dim3(512), 0, stream, Bagg, g0, be0, a0,
                     partS, partQ, Wt1, Ab);
  hipLaunchKernelGGL(k_agg,    dim3(NT_/8),   dim3(256), 0, stream, Ab, rowptr, col, dinv, b1, Bagg, partS, partQ);
  hipLaunchKernelGGL(k_norm_f32, dim3(1024),  dim3(256), 0, stream, Bagg, g1, be1, a1,
                     partS, partQ, out);
}